// Round 14
// baseline (714.157 us; speedup 1.0000x reference)
//
#include <hip/hip_runtime.h>
#include <hip/hip_bf16.h>
#include <cstdint>
#include <cstddef>

// ---------------- problem constants ----------------
constexpr int S_   = 4096;   // sequence
constexpr int DM   = 2048;   // d_model
constexpr int NH   = 16;     // heads
constexpr int DK   = 128;    // head dim
constexpr int DFF  = 5504;   // ffn dim
constexpr int DFFP = 5632;   // ffn dim padded to multiple of 256
constexpr int QLD  = 3 * DM; // qkv buffer row stride (6144)

typedef float  f32x4  __attribute__((ext_vector_type(4)));
typedef float  f32x16 __attribute__((ext_vector_type(16)));
typedef short  s16x8  __attribute__((ext_vector_type(8)));
typedef __bf16 bfx8   __attribute__((ext_vector_type(8)));

// ---------------- MFMA wrappers (robust to builtin signature: short8 vs bf16x8) ----------------
template <typename T, typename U>
__device__ inline auto mfma_try(T a, T b, f32x4 c, int)
    -> decltype(__builtin_amdgcn_mfma_f32_16x16x32_bf16(a, b, c, 0, 0, 0)) {
  return __builtin_amdgcn_mfma_f32_16x16x32_bf16(a, b, c, 0, 0, 0);
}
template <typename T, typename U>
__device__ inline f32x4 mfma_try(T a, T b, f32x4 c, long) {
  U a2 = __builtin_bit_cast(U, a);
  U b2 = __builtin_bit_cast(U, b);
  return __builtin_amdgcn_mfma_f32_16x16x32_bf16(a2, b2, c, 0, 0, 0);
}
__device__ __forceinline__ f32x4 MFMA_BF16(s16x8 a, s16x8 b, f32x4 c) {
  return mfma_try<s16x8, bfx8>(a, b, c, 0);
}

template <typename T, typename U>
__device__ inline auto mfma32_try(T a, T b, f32x16 c, int)
    -> decltype(__builtin_amdgcn_mfma_f32_32x32x16_bf16(a, b, c, 0, 0, 0)) {
  return __builtin_amdgcn_mfma_f32_32x32x16_bf16(a, b, c, 0, 0, 0);
}
template <typename T, typename U>
__device__ inline f32x16 mfma32_try(T a, T b, f32x16 c, long) {
  U a2 = __builtin_bit_cast(U, a);
  U b2 = __builtin_bit_cast(U, b);
  return __builtin_amdgcn_mfma_f32_32x32x16_bf16(a2, b2, c, 0, 0, 0);
}
__device__ __forceinline__ f32x16 MFMA32(s16x8 a, s16x8 b, f32x16 c) {
  return mfma32_try<s16x8, bfx8>(a, b, c, 0);
}

// async global->LDS, 16B per lane; lds base must be wave-uniform (HW adds lane*16)
__device__ __forceinline__ void async_ld16(void* lds, const void* g) {
  __builtin_amdgcn_global_load_lds(
      (__attribute__((address_space(1))) void*)(g),
      (__attribute__((address_space(3))) void*)(lds), 16, 0, 0);
}

__device__ __forceinline__ float bf2f(__hip_bfloat16 h) { return __bfloat162float(h); }
__device__ __forceinline__ __hip_bfloat16 f2bf(float f) { return __float2bfloat16(f); }

// ---------------- fp32 -> bf16 conversion ----------------
__global__ __launch_bounds__(256) void cvt_kernel(const float* __restrict__ in,
                                                  __hip_bfloat16* __restrict__ out, int n) {
  int i = (blockIdx.x * 256 + threadIdx.x) * 4;
  if (i >= n) return;
  float4 v = *reinterpret_cast<const float4*>(in + i);
  union { __hip_bfloat16 h[4]; uint2 u; } pk;
  pk.h[0] = f2bf(v.x); pk.h[1] = f2bf(v.y); pk.h[2] = f2bf(v.z); pk.h[3] = f2bf(v.w);
  *reinterpret_cast<uint2*>(out + i) = pk.u;
}

// three equal-size fp32 matrices -> one contiguous bf16 buffer
__global__ __launch_bounds__(256) void cvt3_kernel(const float* __restrict__ a,
                                                   const float* __restrict__ b,
                                                   const float* __restrict__ c,
                                                   __hip_bfloat16* __restrict__ out, int n) {
  int i = (blockIdx.x * 256 + threadIdx.x) * 4;
  if (i >= 3 * n) return;
  const float* src = (i < n) ? (a + i) : (i < 2 * n) ? (b + i - n) : (c + i - 2 * n);
  float4 v = *reinterpret_cast<const float4*>(src);
  union { __hip_bfloat16 h[4]; uint2 u; } pk;
  pk.h[0] = f2bf(v.x); pk.h[1] = f2bf(v.y); pk.h[2] = f2bf(v.z); pk.h[3] = f2bf(v.w);
  *reinterpret_cast<uint2*>(out + i) = pk.u;
}

// w1,w3 -> interleaved bf16 buffer: B row br = 32g + j; j<16 -> w1[g*16+j], else w3[g*16+j-16].
__global__ __launch_bounds__(256) void cvt_swiglu(const float* __restrict__ w1,
                                                  const float* __restrict__ w3,
                                                  __hip_bfloat16* __restrict__ out) {
  const size_t i = ((size_t)blockIdx.x * 256 + threadIdx.x) * 4;  // < 11264*2048
  const int br = (int)(i >> 11);
  const int k  = (int)(i & 2047);
  const int g  = br >> 5, j = br & 31;
  const int srow = g * 16 + (j & 15);
  union { __hip_bfloat16 h[4]; uint2 u; } pk;
  if (srow < DFF) {
    const float* src = (j < 16 ? w1 : w3) + (size_t)srow * DM + k;
    float4 v = *reinterpret_cast<const float4*>(src);
    pk.h[0] = f2bf(v.x); pk.h[1] = f2bf(v.y); pk.h[2] = f2bf(v.z); pk.h[3] = f2bf(v.w);
  } else {
    pk.u.x = 0u; pk.u.y = 0u;
  }
  *reinterpret_cast<uint2*>(out + i) = pk.u;
}

// ---------------- RMSNorm: fp32 in -> bf16 out ----------------
__global__ __launch_bounds__(256) void rmsnorm_kernel(const float* __restrict__ x,
                                                      const float* __restrict__ g,
                                                      __hip_bfloat16* __restrict__ out) {
  const int row = blockIdx.x, tid = threadIdx.x;
  const float4* xr = reinterpret_cast<const float4*>(x + (size_t)row * DM);
  float4 a = xr[tid], b = xr[tid + 256];
  float ss = a.x*a.x + a.y*a.y + a.z*a.z + a.w*a.w
           + b.x*b.x + b.y*b.y + b.z*b.z + b.w*b.w;
#pragma unroll
  for (int off = 1; off < 64; off <<= 1) ss += __shfl_xor(ss, off);
  __shared__ float red[4];
  if ((tid & 63) == 0) red[tid >> 6] = ss;
  __syncthreads();
  const float inv = rsqrtf((red[0] + red[1] + red[2] + red[3]) * (1.0f / DM) + 1e-5f);
  const float4* gr = reinterpret_cast<const float4*>(g);
  float4 ga = gr[tid], gb = gr[tid + 256];
  union { __hip_bfloat16 h[4]; uint2 u; } pa, pb;
  pa.h[0] = f2bf(a.x * inv * ga.x); pa.h[1] = f2bf(a.y * inv * ga.y);
  pa.h[2] = f2bf(a.z * inv * ga.z); pa.h[3] = f2bf(a.w * inv * ga.w);
  pb.h[0] = f2bf(b.x * inv * gb.x); pb.h[1] = f2bf(b.y * inv * gb.y);
  pb.h[2] = f2bf(b.z * inv * gb.z); pb.h[3] = f2bf(b.w * inv * gb.w);
  uint2* o = reinterpret_cast<uint2*>(out + (size_t)row * DM);
  o[tid] = pa.u; o[tid + 256] = pb.u;
}

// ---------------- RoPE in-place on qkv: Q and K in one pass; Q scaled by log2e/sqrt(dk) ----
__global__ __launch_bounds__(256) void rope_kernel(__hip_bfloat16* __restrict__ t,
                                                   const int* __restrict__ pos) {
  const size_t idx = (size_t)blockIdx.x * 256 + threadIdx.x; // S*NH*64
  const int j = (int)(idx & 63);
  const int h = (int)((idx >> 6) & 15);
  const int s = (int)(idx >> 10);
  const float p = (float)pos[s];
  const float freq = exp2f((float)j * (-13.287712379549449f / 64.0f));
  float sn, cs;
  sincosf(p * freq, &sn, &cs);
  const float cl2 = 1.4426950408889634f * 0.08838834764831845f; // log2e / sqrt(128)
  __hip_bfloat16* ptrQ = t + (size_t)s * QLD + h * DK + 2 * j;
  __hip_bfloat16* ptrK = ptrQ + DM;
  {
    const float e = bf2f(ptrQ[0]), o = bf2f(ptrQ[1]);
    ptrQ[0] = f2bf((e * cs - o * sn) * cl2);
    ptrQ[1] = f2bf((e * sn + o * cs) * cl2);
  }
  {
    const float e = bf2f(ptrK[0]), o = bf2f(ptrK[1]);
    ptrK[0] = f2bf(e * cs - o * sn);
    ptrK[1] = f2bf(e * sn + o * cs);
  }
}

// ---------------- V transpose: qkv[:, 2*DM + h*DK + d] -> vt[h][d][s] ----------------
__global__ __launch_bounds__(256) void transpose_v(const __hip_bfloat16* __restrict__ qkv,
                                                   __hip_bfloat16* __restrict__ vt) {
  __shared__ __hip_bfloat16 tile[64][65];
  const int h = blockIdx.z;
  const int s0 = blockIdx.x * 64, d0 = blockIdx.y * 64;
  const int lane = threadIdx.x & 63, w = threadIdx.x >> 6;
#pragma unroll
  for (int i = 0; i < 16; i++) {
    const int r = w * 16 + i;
    tile[r][lane] = qkv[(size_t)(s0 + r) * QLD + 2 * DM + h * DK + d0 + lane];
  }
  __syncthreads();
#pragma unroll
  for (int i = 0; i < 16; i++) {
    const int r = w * 16 + i;
    vt[(size_t)(h * DK + d0 + r) * S_ + s0 + lane] = tile[lane][r];
  }
}

enum { EP_BF16 = 0, EP_SILU = 1, EP_MUL = 2, EP_ADDF32 = 3, EP_SWIGLU = 4 };

// ================= gemm2 (proven r4/r7 core, 1 barrier/K-tile): BM=128,BN=256,BK=32 ====
template <int EP>
__global__ __launch_bounds__(512, 2) void gemm2(const __hip_bfloat16* __restrict__ A,
                                                const __hip_bfloat16* __restrict__ B,
                                                int N, int K, int lda, int ldb,
                                                void* outp, const void* extra) {
  __shared__ char lds[3][24576];
  const int tid = threadIdx.x;
  const int wave = tid >> 6, lane = tid & 63;
  const int l15 = lane & 15, l4 = lane >> 4;
  const int wm = wave >> 2, wn = wave & 3;

  const int nbn = gridDim.x;
  const int nwg = gridDim.x * gridDim.y;
  int lin = blockIdx.y * gridDim.x + blockIdx.x;
  if ((nwg & 7) == 0) lin = (lin & 7) * (nwg >> 3) + (lin >> 3);
  const int bm = (lin / nbn) * 128;
  const int bn = (lin % nbn) * 256;

  const int NT = K >> 5;

  const int srcCh = ((tid & 3) ^ ((tid >> 3) & 3)) * 16;
  const char* Asrc  = (const char*)A + (size_t)(bm + (tid >> 2)) * lda * 2 + srcCh;
  const char* Bsrc0 = (const char*)B + (size_t)(bn + (tid >> 2)) * ldb * 2 + srcCh;
  const char* Bsrc1 = (const char*)B + (size_t)(bn + 128 + (tid >> 2)) * ldb * 2 + srcCh;
  char* const ldsA  = &lds[0][0] + wave * 1024;
  char* const ldsB0 = &lds[0][0] + 8192 + wave * 1024;
  char* const ldsB1 = &lds[0][0] + 16384 + wave * 1024;

  auto stage_a  = [&](int t, int s) { async_ld16(ldsA  + s * 24576, Asrc  + (size_t)t * 64); };
  auto stage_b0 = [&](int t, int s) { async_ld16(ldsB0 + s * 24576, Bsrc0 + (size_t)t * 64); };
  auto stage_b1 = [&](int t, int s) { async_ld16(ldsB1 + s * 24576, Bsrc1 + (size_t)t * 64); };

  const int rdch = (l4 ^ ((l15 >> 1) & 3)) * 16;
  auto rd_a = [&](int s, int mq, int f) -> s16x8 {
    return *(const s16x8*)(&lds[s][0] + (wm * 64 + mq * 32 + f * 16 + l15) * 64 + rdch);
  };
  auto rd_b = [&](int s, int nf) -> s16x8 {
    return *(const s16x8*)(&lds[s][8192] + (wn * 64 + nf * 16 + l15) * 64 + rdch);
  };

  f32x4 acc[4][4] = {};

  stage_a(0, 0); stage_b0(0, 0); stage_b1(0, 0);
  stage_a(1, 1); stage_b0(1, 1); stage_b1(1, 1);

  for (int t = 0; t < NT; t++) {
    const int s = t % 3;
    if (t + 1 < NT) { asm volatile("s_waitcnt vmcnt(3)" ::: "memory"); }
    else            { asm volatile("s_waitcnt vmcnt(0)" ::: "memory"); }
    __builtin_amdgcn_s_barrier();
    asm volatile("" ::: "memory");
    s16x8 b0 = rd_b(s, 0), b1 = rd_b(s, 1), b2 = rd_b(s, 2), b3 = rd_b(s, 3);
    s16x8 a0 = rd_a(s, 0, 0), a1 = rd_a(s, 0, 1);
    if (t + 2 < NT) { const int s2 = (t + 2) % 3; stage_a(t + 2, s2); stage_b0(t + 2, s2); }
    __builtin_amdgcn_s_setprio(1);
    acc[0][0] = MFMA_BF16(a0, b0, acc[0][0]);
    acc[0][1] = MFMA_BF16(a0, b1, acc[0][1]);
    acc[0][2] = MFMA_BF16(a0, b2, acc[0][2]);
    acc[0][3] = MFMA_BF16(a0, b3, acc[0][3]);
    acc[1][0] = MFMA_BF16(a1, b0, acc[1][0]);
    acc[1][1] = MFMA_BF16(a1, b1, acc[1][1]);
    acc[1][2] = MFMA_BF16(a1, b2, acc[1][2]);
    acc[1][3] = MFMA_BF16(a1, b3, acc[1][3]);
    __builtin_amdgcn_s_setprio(0);
    s16x8 a2 = rd_a(s, 1, 0), a3 = rd_a(s, 1, 1);
    if (t + 2 < NT) stage_b1(t + 2, (t + 2) % 3);
    __builtin_amdgcn_s_setprio(1);
    acc[2][0] = MFMA_BF16(a2, b0, acc[2][0]);
    acc[2][1] = MFMA_BF16(a2, b1, acc[2][1]);
    acc[2][2] = MFMA_BF16(a2, b2, acc[2][2]);
    acc[2][3] = MFMA_BF16(a2, b3, acc[2][3]);
    acc[3][0] = MFMA_BF16(a3, b0, acc[3][0]);
    acc[3][1] = MFMA_BF16(a3, b1, acc[3][1]);
    acc[3][2] = MFMA_BF16(a3, b2, acc[3][2]);
    acc[3][3] = MFMA_BF16(a3, b3, acc[3][3]);
    __builtin_amdgcn_s_setprio(0);
  }

#pragma unroll
  for (int mf = 0; mf < 4; mf++)
#pragma unroll
    for (int nf = 0; nf < 4; nf++)
#pragma unroll
      for (int r = 0; r < 4; r++) {
        const int row = bm + wm * 64 + mf * 16 + l4 * 4 + r;
        const int col = bn + wn * 64 + nf * 16 + l15;
        const size_t idx = (size_t)row * N + col;
        const float v = acc[mf][nf][r];
        if constexpr (EP == EP_BF16) {
          ((__hip_bfloat16*)outp)[idx] = f2bf(v);
        } else if constexpr (EP == EP_SILU) {
          ((__hip_bfloat16*)outp)[idx] = f2bf(v / (1.0f + __expf(-v)));
        } else if constexpr (EP == EP_MUL) {
          const float o = bf2f(((const __hip_bfloat16*)extra)[idx]);
          ((__hip_bfloat16*)outp)[idx] = f2bf(v * o);
        } else { // EP_ADDF32
          ((float*)outp)[idx] = v + ((const float*)extra)[idx];
        }
      }
}

// ================= gemm2s: 4-wave shrink of gemm2 — BM=BN=128, 48KB LDS ================
// Same 3-slot counted-vmcnt ledger (4 asyncs/tile => vmcnt(4)), same 1-barrier/K-tile
// race proof (wave-count independent). 256 threads; grid 512 blocks => 2/CU co-residency
// for the N=2048 GEMMs (WO, W2) that ran at 1 block/CU on gemm2.
template <int EP>
__global__ __launch_bounds__(256, 3) void gemm2s(const __hip_bfloat16* __restrict__ A,
                                                 const __hip_bfloat16* __restrict__ B,
                                                 int N, int K, int lda, int ldb,
                                                 void* outp, const void* extra) {
  __shared__ char lds[3][16384];   // per slot: A[128][64B] @0, B[128][64B] @8192
  const int tid = threadIdx.x;
  const int wave = tid >> 6, lane = tid & 63;
  const int l15 = lane & 15, l4 = lane >> 4;
  const int wm = wave >> 1, wn = wave & 1;

  const int nbn = gridDim.x;
  const int nwg = gridDim.x * gridDim.y;
  int lin = blockIdx.y * gridDim.x + blockIdx.x;
  if ((nwg & 7) == 0) lin = (lin & 7) * (nwg >> 3) + (lin >> 3);
  const int bm = (lin / nbn) * 128;
  const int bn = (lin % nbn) * 128;

  const int NT = K >> 5;

  // row = tid>>2 (0..63); swizzle term (row>>1)&3 == (tid>>3)&3 for both row and row+64
  const int srcCh = ((tid & 3) ^ ((tid >> 3) & 3)) * 16;
  const char* Asrc0 = (const char*)A + (size_t)(bm + (tid >> 2)) * lda * 2 + srcCh;
  const char* Asrc1 = (const char*)A + (size_t)(bm + 64 + (tid >> 2)) * lda * 2 + srcCh;
  const char* Bsrc0 = (const char*)B + (size_t)(bn + (tid >> 2)) * ldb * 2 + srcCh;
  const char* Bsrc1 = (const char*)B + (size_t)(bn + 64 + (tid >> 2)) * ldb * 2 + srcCh;
  char* const ldsA0 = &lds[0][0] + wave * 1024;          // rows 0..63
  char* const ldsA1 = &lds[0][0] + 4096 + wave * 1024;   // rows 64..127
  char* const ldsB0 = &lds[0][0] + 8192 + wave * 1024;
  char* const ldsB1 = &lds[0][0] + 12288 + wave * 1024;

  auto stage_a0 = [&](int t, int s) { async_ld16(ldsA0 + s * 16384, Asrc0 + (size_t)t * 64); };
  auto stage_a1 = [&](int t, int s) { async_ld16(ldsA1 + s * 16384, Asrc1 + (size_t)t * 64); };
  auto stage_b0 = [&](int t, int s) { async_ld16(ldsB0 + s * 16384, Bsrc0 + (size_t)t * 64); };
  auto stage_b1 = [&](int t, int s) { async_ld16(ldsB1 + s * 16384, Bsrc1 + (size_t)t * 64); };

  const int rdch = (l4 ^ ((l15 >> 1) & 3)) * 16;
  auto rd_a = [&](int s, int mq, int f) -> s16x8 {
    return *(const s16x8*)(&lds[s][0] + (wm * 64 + mq * 32 + f * 16 + l15) * 64 + rdch);
  };
  auto rd_b = [&](int s, int nf) -> s16x8 {
    return *(const s16x8*)(&lds[s][8192] + (wn * 64 + nf * 16 + l15) * 64 + rdch);
  };

  f32x4 acc[4][4] = {};

  stage_a0(0, 0); stage_a1(0, 0); stage_b0(0, 0); stage_b1(0, 0);
  stage_a0(1, 1); stage_a1(1, 1); stage_b0(1, 1); stage_b1(1, 1);

  for (int t = 0; t < NT; t++) {
    const int s = t % 3;
    if (t + 1 < NT) { asm volatile("s_waitcnt vmcnt(4)" ::: "memory"); }
    else            { asm volatile("s_waitcnt vmcnt(0)" ::: "memory"); }
    __builtin_amdgcn_s_barrier();
    asm volatile("" ::: "memory");
    s16x8 b0 = rd_b(s, 0), b1 = rd_b(s, 1), b2 = rd_b(s, 2), b3 = rd_b(s, 3);
    s16x8 a0 = rd_a(s, 0, 0), a1 = rd_a(s, 0, 1);
    if (t + 2 < NT) { const int s2 = (t + 2) % 3; stage_a0(t + 2, s2); stage_a1(t + 2, s2); }
    __builtin_amdgcn_s_setprio(1);
    acc[0][0] = MFMA_BF16(a0, b0, acc[0][0]);
    acc[0][1] = MFMA_BF16(a0, b1, acc[0][1]);
    acc[0][2] = MFMA_BF16(a0, b2, acc[0][2]);
    acc[0][3] = MFMA_BF16(a0, b3, acc[0][3]);
    acc[1][0] = MFMA_BF16(a1, b0, acc[1][0]);
    acc[1][1] = MFMA_BF16(a1, b1, acc[1][1]);
    acc[1][2] = MFMA_BF16(a1, b2, acc[1][2]);
    acc[1][3] = MFMA_BF16(a1, b3, acc[1][3]);
    __builtin_amdgcn_s_setprio(0);
    s16x8 a2 = rd_a(s, 1, 0), a3 = rd_a(s, 1, 1);
    if (t + 2 < NT) { const int s2 = (t + 2) % 3; stage_b0(t + 2, s2); stage_b1(t + 2, s2); }
    __builtin_amdgcn_s_setprio(1);
    acc[2][0] = MFMA_BF16(a2, b0, acc[2][0]);
    acc[2][1] = MFMA_BF16(a2, b1, acc[2][1]);
    acc[2][2] = MFMA_BF16(a2, b2, acc[2][2]);
    acc[2][3] = MFMA_BF16(a2, b3, acc[2][3]);
    acc[3][0] = MFMA_BF16(a3, b0, acc[3][0]);
    acc[3][1] = MFMA_BF16(a3, b1, acc[3][1]);
    acc[3][2] = MFMA_BF16(a3, b2, acc[3][2]);
    acc[3][3] = MFMA_BF16(a3, b3, acc[3][3]);
    __builtin_amdgcn_s_setprio(0);
  }

#pragma unroll
  for (int mf = 0; mf < 4; mf++)
#pragma unroll
    for (int nf = 0; nf < 4; nf++)
#pragma unroll
      for (int r = 0; r < 4; r++) {
        const int row = bm + wm * 64 + mf * 16 + l4 * 4 + r;
        const int col = bn + wn * 64 + nf * 16 + l15;
        const size_t idx = (size_t)row * N + col;
        const float v = acc[mf][nf][r];
        if constexpr (EP == EP_ADDF32) {
          ((float*)outp)[idx] = v + ((const float*)extra)[idx];
        } else {
          ((__hip_bfloat16*)outp)[idx] = f2bf(v);
        }
      }
}

// ================= gemm4 (r10 proven form): BM=BN=256, BK=32, 4-slot, depth-3 ============
template <int EP>
__global__ __launch_bounds__(512, 1) void gemm4(const __hip_bfloat16* __restrict__ A,
                                                const __hip_bfloat16* __restrict__ B,
                                                int N, int K, int lda, int ldb,
                                                void* outp, const void* extra) {
  __shared__ char lds[4][32768];   // slot: A[256][64B] @0, B[256][64B] @16384
  const int tid = threadIdx.x;
  const int wave = tid >> 6, lane = tid & 63;
  const int l15 = lane & 15, l4 = lane >> 4;
  const int wm = wave >> 2, wn = wave & 3;   // wm 0..1, wn 0..3

  const int nbn = gridDim.x;
  const int nwg = gridDim.x * gridDim.y;
  int lin = blockIdx.y * gridDim.x + blockIdx.x;
  if ((nwg & 7) == 0) lin = (lin & 7) * (nwg >> 3) + (lin >> 3);
  const int bm = (lin / nbn) * 256;
  const int bn = (lin % nbn) * 256;

  const int NT = K >> 5;

  const int srcCh = ((tid & 3) ^ ((tid >> 3) & 3)) * 16;
  const char* Asrc0 = (const char*)A + (size_t)(bm + (tid >> 2)) * lda * 2 + srcCh;
  const char* Asrc1 = (const char*)A + (size_t)(bm + 128 + (tid >> 2)) * lda * 2 + srcCh;
  const char* Bsrc0 = (const char*)B + (size_t)(bn + (tid >> 2)) * ldb * 2 + srcCh;
  const char* Bsrc1 = (const char*)B + (size_t)(bn + 128 + (tid >> 2)) * ldb * 2 + srcCh;
  char* const ldsA0 = &lds[0][0] + wave * 1024;
  char* const ldsA1 = &lds[0][0] + 8192 + wave * 1024;
  char* const ldsB0 = &lds[0][0] + 16384 + wave * 1024;
  char* const ldsB1 = &lds[0][0] + 24576 + wave * 1024;

  auto stage_a0 = [&](int t, int s) { async_ld16(ldsA0 + s * 32768, Asrc0 + (size_t)t * 64); };
  auto stage_a1 = [&](int t, int s) { async_ld16(ldsA1 + s * 32768, Asrc1 + (size_t)t * 64); };
  auto stage_b0 = [&](int t, int s) { async_ld16(ldsB0 + s * 32768, Bsrc0 + (size_t)t * 64); };
  auto stage_b1 = [&](int t, int s) { async_ld16(ldsB1 + s * 32768, Bsrc1 + (size_t)t * 64); };

  const int rdch = (l4 ^ ((l15 >> 1) & 3)) * 16;
  auto rd_a = [&](int s, int mf) -> s16x8 {
    return *(const s16x8*)(&lds[s][0] + (wm * 128 + mf * 16 + l15) * 64 + rdch);
  };
  auto rd_b = [&](int s, int nf) -> s16x8 {
    return *(const s16x8*)(&lds[s][16384] + (wn * 64 + nf * 16 + l15) * 64 + rdch);
  };

  f32x4 acc[8][4] = {};

#pragma unroll
  for (int t = 0; t < 3; t++) {
    stage_a0(t, t); stage_a1(t, t); stage_b0(t, t); stage_b1(t, t);
  }

  for (int t = 0; t < NT; t++) {
    const int s = t & 3;
    if (t + 1 < NT) { asm volatile("s_waitcnt vmcnt(8)" ::: "memory"); }
    else            { asm volatile("s_waitcnt vmcnt(0)" ::: "memory"); }
    __builtin_amdgcn_s_barrier();
    asm volatile("" ::: "memory");
    const int s3 = (t + 3) & 3;
    const bool pf = (t + 3 < NT);
    s16x8 b0 = rd_b(s, 0), b1 = rd_b(s, 1), b2 = rd_b(s, 2), b3 = rd_b(s, 3);
    // phase 0
    s16x8 a0 = rd_a(s, 0), a1 = rd_a(s, 1);
    if (pf) stage_a0(t + 3, s3);
    __builtin_amdgcn_s_setprio(1);
    acc[0][0] = MFMA_BF16(a0, b0, acc[0][0]);
    acc[0][1] = MFMA_BF16(a0, b1, acc[0][1]);
    acc[0][2] = MFMA_BF16(a0, b2, acc[0][2]);
    acc[0][3] = MFMA_BF16(a0, b3, acc[0][3]);
    acc[1][0] = MFMA_BF16(a1, b0, acc[1][0]);
    acc[1][1] = MFMA_BF16(a1, b1, acc[1][1]);
    acc[1][2] = MFMA_BF16(a1, b2, acc[1][2]);
    acc[1][3] = MFMA_BF16(a1, b3, acc[1][3]);
    __builtin_amdgcn_s_setprio(0);
    // phase 1
    s16x8 a2 = rd_a(s, 2), a3 = rd_a(s, 3);
    if (pf) stage_a1(t + 3, s3);
    __builtin_amdgcn_s_setprio(1);
    acc[2][0] = MFMA_BF16(a2, b0, acc[2][0]);
    acc[2][1] = MFMA_BF16(a2, b1, acc[2][1]);
    acc[2][2] = MFMA_BF16(a2, b2, acc[2][2]);
    acc[2][3] = MFMA_BF16(a2, b3, acc[2][3]);
    acc[3][0] = MFMA_BF16(a3, b0, acc[3][0]);
    acc[3][1] = MFMA_BF16(a3, b1, acc[3][1]);
    acc[3][2] = MFMA_BF16(a3, b2, acc[3][2]);
    acc[3][3] = MFMA_BF16(a3, b3, acc[3][3]);
    __builtin_amdgcn_s_setprio(0);
    // phase 2
    s16x8 a4 = rd_a(s, 4), a5 = rd_a(s, 5);
    if (pf) stage_b0(t + 3, s3);
    __builtin_amdgcn_s_setprio(1);
    acc[4][0] = MFMA_BF16(a4, b0, acc[4][0]);
    acc[4][1] = MFMA_BF16(a4, b1, acc[4][1]);
    acc[4][2] = MFMA_BF16(a4, b2, acc[4][2]);
    acc[4][3] = MFMA_BF16(a4, b3, acc[4][3]);
    acc[5][0] = MFMA_BF16(a5, b0, acc[5][0]);
    acc[5][1] = MFMA_BF16(a5, b1, acc[5][1]);
    acc[5][2] = MFMA_BF16(a5, b2, acc[5][2]);
    acc[5][3] = MFMA_BF16(a5, b3, acc[5][3]);
    __builtin_amdgcn_s_setprio(0);
    // phase 3
    s16x8 a6 = rd_a(s, 6), a7 = rd_a(s, 7);
    if (pf) stage_b1(t + 3, s3);
    __builtin_amdgcn_s_setprio(1);
    acc[6][0] = MFMA_BF16(a6, b0, acc[6][0]);
    acc[6][1] = MFMA_BF16(a6, b1, acc[6][1]);
    acc[6][2] = MFMA_BF16(a6, b2, acc[6][2]);
    acc[6][3] = MFMA_BF16(a6, b3, acc[6][3]);
    acc[7][0] = MFMA_BF16(a7, b0, acc[7][0]);
    acc[7][1] = MFMA_BF16(a7, b1, acc[7][1]);
    acc[7][2] = MFMA_BF16(a7, b2, acc[7][2]);
    acc[7][3] = MFMA_BF16(a7, b3, acc[7][3]);
    __builtin_amdgcn_s_setprio(0);
  }

  if constexpr (EP == EP_SWIGLU) {
#pragma unroll
    for (int mf = 0; mf < 8; mf++)
#pragma unroll
      for (int pp = 0; pp < 2; pp++)
#pragma unroll
        for (int r = 0; r < 4; r++) {
          const int row = bm + wm * 128 + mf * 16 + l4 * 4 + r;
          const int col = (bn >> 1) + wn * 32 + pp * 16 + l15;
          const float gt = acc[mf][pp * 2][r];
          const float up = acc[mf][pp * 2 + 1][r];
          ((__hip_bfloat16*)outp)[(size_t)row * N + col] =
              f2bf(gt / (1.0f + __expf(-gt)) * up);
        }
    return;
  }

#pragma unroll
  for (int mf = 0; mf < 8; mf++)
#pragma unroll
    for (int nf = 0; nf < 4; nf++)
#pragma unroll
      for (int r = 0; r < 4; r++) {
        const int row = bm + wm * 128 + mf * 16 + l4 * 4 + r;
        const int col = bn + wn * 64 + nf * 16 + l15;
        const size_t idx = (size_t)row * N + col;
        const float v = acc[mf][nf][r];
        if constexpr (EP == EP_ADDF32) {
          ((float*)outp)[idx] = v + ((const float*)extra)[idx];
        } else {
          ((__hip_bfloat16*)outp)[idx] = f2bf(v);
        }
      }
}

// ---------------- causal flash attention (r9 v4, best measured: pairing + K/V dbuf) -----
__global__ __launch_bounds__(256, 2) void attn_kernel(const __hip_bfloat16* __restrict__ qkv,
                                                      const __hip_bfloat16* __restrict__ vt,
                                                      __hip_bfloat16* __restrict__ out) {
  __shared__ char sK[2][64 * 256];  // [kv][d] 2x16KB
  __shared__ char sV[2][128 * 128]; // [d][kv] 2x16KB

  const int h = blockIdx.y;
  int qt = (blockIdx.x + 2 * (h & 7)) & 31;
  if (h >= 8) qt = 31 - qt;
  const int qtile = qt;
  const int q0 = qtile * 128;
  const int tid = threadIdx.x, wave = tid >> 6, lane = tid & 63;
  const int l31 = lane & 31, hi = lane >> 5;
  const int qr = q0 + wave * 32 + l31;           // this lane's q row
  const int ntiles = qtile * 2 + 2;

  s16x8 qf[8];
  {
    const char* qsrc = (const char*)qkv + (size_t)qr * (QLD * 2) + h * DK * 2 + hi * 16;
#pragma unroll
    for (int s = 0; s < 8; s++) qf[s] = *(const s16x8*)(qsrc + s * 32);
  }

  const char* qkvK = (const char*)qkv + ((size_t)DM + h * DK) * 2;
  const char* vtH  = (const char*)vt + (size_t)h * DK * S_ * 2;

  auto stage_K = [&](int t, int buf) {
    const int kv0 = t * 64;
#pragma unroll
    for (int a = 0; a < 4; a++) {
      const int rl = wave * 16 + a * 4 + (lane >> 4);
      const int ck = (lane & 15) ^ (rl & 7);
      async_ld16(sK[buf] + (wave * 16 + a * 4) * 256,
                 qkvK + (size_t)(kv0 + rl) * (QLD * 2) + ck * 16);
    }
  };
  auto stage_V = [&](int t, int buf) {
    const int kv0 = t * 64;
#pragma unroll
    for (int a = 0; a < 4; a++) {
      const int rl = wave * 32 + a * 8 + (lane >> 3);
      const int cv = (lane & 7) ^ (rl & 7);
      async_ld16(sV[buf] + (wave * 32 + a * 8) * 128,
                 vtH + ((size_t)rl * S_ + kv0) * 2 + cv * 16);
    }
  };

  f32x16 acc[4] = {};
  float m_ = -__builtin_inff(), l_ = 0.f;

  stage_K(0, 0);
  stage_V(0, 0);

  int buf = 0;
  for (int t = 0; t < ntiles; t++) {
    if (t + 1 < ntiles) {
      stage_K(t + 1, buf ^ 1);
      stage_V(t + 1, buf ^ 1);
      asm volatile("s_waitcnt vmcnt(8)" ::: "memory");
    } else {
      asm volatile("s_waitcnt vmcnt(0)" ::: "memory");
    }
    __builtin_amdgcn_s_barrier();

    const char* Kt = sK[buf];
    const char* Vt = sV[buf];

    f32x16 st0 = {}, st1 = {};
    __builtin_amdgcn_s_setprio(1);
#pragma unroll
    for (int s = 0; s < 8; s++) {
      const int cc = s * 2 + hi;
      const int cs = (cc & 8) | ((cc ^ l31) & 7);
      s16x8 k0 = *(const s16x8*)(Kt + l31 * 256 + cs * 16);
      s16x8 k1 = *(const s16x8*)(Kt + (32 + l31) * 256 + cs * 16);
      st0 = MFMA32(k0, qf[s], st0);
      st1 = MFMA32(k1, qf[s], st1);
    }
    __builtin_amdgcn_s_setprio(0);

    const int kvb = t * 64;
    float p[32];
    float mx = -__builtin_inff();
    if (kvb + 63 <= q0 + wave * 32) {
#pragma unroll
      for (int r = 0; r < 16; r++) {
        p[r]      = st0[r];
        p[16 + r] = st1[r];
        mx = fmaxf(mx, fmaxf(p[r], p[16 + r]));
      }
    } else {
#pragma unroll
      for (int r = 0; r < 16; r++) {
        const int kv = kvb + (r & 3) + 8 * (r >> 2) + 4 * hi;
        p[r]      = (kv <= qr)      ? st0[r] : -__builtin_inff();
        p[16 + r] = (kv + 32 <= qr) ? st1[r] : -__builtin_inff();
        mx = fmaxf(mx, fmaxf(p[r], p[16 + r]));
      }
    }
    mx = fmaxf(mx, __shfl_xor(mx, 32));
    const bool skip = __all(mx - m_ <= 8.0f);
    float alpha = 1.0f;
    if (!skip) {
      const float nm = fmaxf(m_, mx);
      alpha = exp2f(m_ - nm);
      m_ = nm;
#pragma unroll
      for (int dt = 0; dt < 4; dt++)
#pragma unroll
        for (int r = 0; r < 16; r++) acc[dt][r] *= alpha;
    }
    float psum = 0.f;
#pragma unroll
    for (int i = 0; i < 32; i++) {
      p[i] = exp2f(p[i] - m_);
      psum += p[i];
    }
    psum += __shfl_xor(psum, 32);
    l_ = l_ * alpha + psum;

    unsigned ps[16];
#pragma unroll
    for (int h2 = 0; h2 < 2; h2++)
#pragma unroll
      for (int t2 = 0; t2 < 4; t2++)
#pragma unroll
        for (int rp = 0; rp < 2; rp++) {
          union { __hip_bfloat16 hh[2]; unsigned u; } pk;
          pk.hh[0] = f2bf(p[h2 * 16 + t2 * 4 + rp * 2]);
          pk.hh[1] = f2bf(p[h2 * 16 + t2 * 4 + rp * 2 + 1]);
          ps[h2 * 8 + t2 * 2 + rp] = pk.u;
        }

#pragma unroll
    for (int s = 0; s < 4; s++) {
      const int h2 = s >> 1;
      const int iA = h2 * 8 + (2 * (s & 1)) * 2;
      const int iB = h2 * 8 + (2 * (s & 1) + 1) * 2;
      const unsigned keep0 = hi ? ps[iB]     : ps[iA];
      const unsigned keep1 = hi ? ps[iB + 1] : ps[iA + 1];
      const unsigned send0 = hi ? ps[iA]     : ps[iB];
      const unsigned send1 = hi ? ps[iA + 1] : ps[iB + 1];
      const unsigned recv0 = __shfl_xor(send0, 32);
      const unsigned recv1 = __shfl_xor(send1, 32);
      union { unsigned u[4]; s16x8 v; } fr;
      fr.u[0] = hi ? recv0 : keep0;
      fr.u[1] = hi ? recv1 : keep1;
      fr.u[2] = hi ? keep0 : recv0;
      fr.u[3] = hi ? keep1 : recv1;
      const s16x8 pa = fr.v;
      __builtin_amdgcn_s_setprio(1);
#pragma unroll
      for (int dt = 0; dt < 4; dt++) {
        s16x8 vf = *(const s16x8*)(Vt + (dt * 32 + l31) * 128 +
                                   (((s * 2 + hi) ^ (l31 & 7)) & 7) * 16);
        acc[dt] = MFMA32(vf, pa, acc[dt]);
      }
      __builtin_amdgcn_s_setprio(0);
    }

    if (t + 2 < ntiles) __builtin_amdgcn_s_barrier();
    buf ^= 1;
  }

  const float rl = 1.0f / l_;
  __hip_bfloat16* orow = out + (size_t)qr * DM + h * DK;
#pragma unroll
  for (int dt = 0; dt < 4; dt++)
#pragma unroll
    for (int rq = 0; rq < 4; rq++) {
      union { __hip_bfloat16 hh[4]; uint2 u; } pk;
#pragma unroll
      for (int e = 0; e < 4; e++) pk.hh[e] = f2bf(acc[dt][rq * 4 + e] * rl);
      *reinterpret_cast<uint2*>(orow + dt * 32 + 8 * rq + 4 * hi) = pk.u;
    }
}

// ---------------- host launcher ----------------
// Workspace (109,051,904 B), phase-overlaid (same as round 9):
//  attn phase: wqkv@0 (25.2M) [attnb@8.4M after], xn@25.2M (16.8M), qkv@42M (50.3M), vt@92.3M (16.8M)
//  WO:         wo@0 (8.4M), attnb@8.4M, x1 -> d_out
//  FFN phase:  xn2@0 (16.8M), wfused@16.8M (46.1M), ff1@62.9M (46.1M); then w2@0 (22.5M)
extern "C" void kernel_launch(void* const* d_in, const int* in_sizes, int n_in,
                              void* d_out, int out_size, void* d_ws, size_t ws_size,
                              hipStream_t stream) {
  const float* x   = (const float*)d_in[0];
  const float* w_q = (const float*)d_in[1];
  const float* w_k = (const float*)d_in[2];
  const float* w_v = (const float*)d_in[3];
  const float* w_o = (const float*)d_in[4];
  const float* w1  = (const float*)d_in[5];
  const float* w2  = (const float*)d_in[6];
  const float* w3  = (const float*)d_in[7];
  const float* g1  = (const float*)d_in[8];
  const float* g2  = (const float*)d_in[9];
  const int*   tp  = (const int*)d_in[10];
  float* outf = (float*)d_out;

  constexpr size_t SZ_WQKV  = (size_t)3 * DM * DM * 2;
  constexpr size_t OFF_ATTN = (size_t)DM * DM * 2;
  constexpr size_t OFF_XN   = SZ_WQKV;
  constexpr size_t OFF_A2   = OFF_XN + (size_t)S_ * DM * 2;
  constexpr size_t OFF_VT   = OFF_A2 + (size_t)S_ * QLD * 2;
  constexpr size_t WS_NEED  = OFF_VT + (size_t)NH * DK * S_ * 2;
  constexpr size_t OFF_WF   = (size_t)S_ * DM * 2;
  constexpr size_t OFF_FF1  = OFF_WF + (size_t)2 * DFFP * DM * 2;
  static_assert(OFF_FF1 + (size_t)S_ * DFFP * 2 == WS_NEED, "ws layout");
  if (ws_size < WS_NEED) return;

  char* base = (char*)d_ws;
  __hip_bfloat16* warena = (__hip_bfloat16*)base;
  __hip_bfloat16* attnb  = (__hip_bfloat16*)(base + OFF_ATTN);
  __hip_bfloat16* xn     = (__hip_bfloat16*)(base + OFF_XN);
  __hip_bfloat16* qkv    = (__hip_bfloat16*)(base + OFF_A2);
  __hip_bfloat16* vt     = (__hip_bfloat16*)(base + OFF_VT);
  __hip_bfloat16* xn2    = (__hip_bfloat16*)base;
  __hip_bfloat16* wfused = (__hip_bfloat16*)(base + OFF_WF);
  __hip_bfloat16* ff1    = (__hip_bfloat16*)(base + OFF_FF1);

  const int nwq = DM * DM;

  // --- attention phase ---
  cvt3_kernel<<<(3 * nwq) / 1024, 256, 0, stream>>>(w_q, w_k, w_v, warena, nwq);
  rmsnorm_kernel<<<S_, 256, 0, stream>>>(x, g1, xn);
  // qkv = xn @ Wqkv^T : gemm2, grid 24x32=768 (%8==0, 2 blocks/CU)
  gemm2<EP_BF16><<<dim3(QLD / 256, S_ / 128), 512, 0, stream>>>(xn, warena, QLD, DM, DM, DM, qkv, nullptr);
  rope_kernel<<<(S_ * NH * 64) / 256, 256, 0, stream>>>(qkv, tp);
  transpose_v<<<dim3(S_ / 64, DK / 64, NH), 256, 0, stream>>>(qkv, vt);
  // attn v4: grid 32x16=512 blocks, 4 waves, 2 blocks/CU, complementary pairing
  attn_kernel<<<dim3(S_ / 128, NH), 256, 0, stream>>>(qkv, vt, attnb);
  // x1 = x + attn @ Wo^T : gemm2s, grid 16x32=512 (%8==0, 2/CU)
  cvt_kernel<<<nwq / 1024, 256, 0, stream>>>(w_o, warena, nwq);
  gemm2s<EP_ADDF32><<<dim3(DM / 128, S_ / 128), 256, 0, stream>>>(attnb, warena, DM, DM, DM, DM, outf, x);

  // --- FFN phase ---
  rmsnorm_kernel<<<S_, 256, 0, stream>>>(outf, g2, xn2);
  cvt_swiglu<<<(2 * DFFP * DM) / 1024, 256, 0, stream>>>(w1, w3, wfused);
  // ff1 = silu(xn2 @ W1^T) * (xn2 @ W3^T) : gemm4 (r10 form), grid 44x16=704, out stride DFFP
  gemm4<EP_SWIGLU><<<dim3((2 * DFFP) / 256, S_ / 256), 512, 0, stream>>>(xn2, wfused, DFFP, DM, DM, DM, ff1, nullptr);
  // out = x1 + ff1 @ W2^T : gemm2s, K=5504, lda=5632 (pad stride), grid 16x32=512
  cvt_kernel<<<(DM * DFF) / 1024, 256, 0, stream>>>(w2, warena, DM * DFF);
  gemm2s<EP_ADDF32><<<dim3(DM / 128, S_ / 128), 256, 0, stream>>>(ff1, warena, DM, DFF, DFFP, DFF, outf, outf);
}

// Round 15
// 691.336 us; speedup vs baseline: 1.0330x; 1.0330x over previous
//
#include <hip/hip_runtime.h>
#include <hip/hip_bf16.h>
#include <cstdint>
#include <cstddef>

// ---------------- problem constants ----------------
constexpr int S_   = 4096;   // sequence
constexpr int DM   = 2048;   // d_model
constexpr int NH   = 16;     // heads
constexpr int DK   = 128;    // head dim
constexpr int DFF  = 5504;   // ffn dim
constexpr int DFFP = 5632;   // ffn dim padded to multiple of 256
constexpr int QLD  = 3 * DM; // qkv buffer row stride (6144)

typedef float  f32x4  __attribute__((ext_vector_type(4)));
typedef float  f32x16 __attribute__((ext_vector_type(16)));
typedef short  s16x8  __attribute__((ext_vector_type(8)));
typedef __bf16 bfx8   __attribute__((ext_vector_type(8)));

// ---------------- MFMA wrappers (robust to builtin signature: short8 vs bf16x8) ----------------
template <typename T, typename U>
__device__ inline auto mfma_try(T a, T b, f32x4 c, int)
    -> decltype(__builtin_amdgcn_mfma_f32_16x16x32_bf16(a, b, c, 0, 0, 0)) {
  return __builtin_amdgcn_mfma_f32_16x16x32_bf16(a, b, c, 0, 0, 0);
}
template <typename T, typename U>
__device__ inline f32x4 mfma_try(T a, T b, f32x4 c, long) {
  U a2 = __builtin_bit_cast(U, a);
  U b2 = __builtin_bit_cast(U, b);
  return __builtin_amdgcn_mfma_f32_16x16x32_bf16(a2, b2, c, 0, 0, 0);
}
__device__ __forceinline__ f32x4 MFMA_BF16(s16x8 a, s16x8 b, f32x4 c) {
  return mfma_try<s16x8, bfx8>(a, b, c, 0);
}

template <typename T, typename U>
__device__ inline auto mfma32_try(T a, T b, f32x16 c, int)
    -> decltype(__builtin_amdgcn_mfma_f32_32x32x16_bf16(a, b, c, 0, 0, 0)) {
  return __builtin_amdgcn_mfma_f32_32x32x16_bf16(a, b, c, 0, 0, 0);
}
template <typename T, typename U>
__device__ inline f32x16 mfma32_try(T a, T b, f32x16 c, long) {
  U a2 = __builtin_bit_cast(U, a);
  U b2 = __builtin_bit_cast(U, b);
  return __builtin_amdgcn_mfma_f32_32x32x16_bf16(a2, b2, c, 0, 0, 0);
}
__device__ __forceinline__ f32x16 MFMA32(s16x8 a, s16x8 b, f32x16 c) {
  return mfma32_try<s16x8, bfx8>(a, b, c, 0);
}

// async global->LDS, 16B per lane; lds base must be wave-uniform (HW adds lane*16)
__device__ __forceinline__ void async_ld16(void* lds, const void* g) {
  __builtin_amdgcn_global_load_lds(
      (__attribute__((address_space(1))) void*)(g),
      (__attribute__((address_space(3))) void*)(lds), 16, 0, 0);
}

__device__ __forceinline__ float bf2f(__hip_bfloat16 h) { return __bfloat162float(h); }
__device__ __forceinline__ __hip_bfloat16 f2bf(float f) { return __float2bfloat16(f); }

// ---------------- fp32 -> bf16 conversion ----------------
__global__ __launch_bounds__(256) void cvt_kernel(const float* __restrict__ in,
                                                  __hip_bfloat16* __restrict__ out, int n) {
  int i = (blockIdx.x * 256 + threadIdx.x) * 4;
  if (i >= n) return;
  float4 v = *reinterpret_cast<const float4*>(in + i);
  union { __hip_bfloat16 h[4]; uint2 u; } pk;
  pk.h[0] = f2bf(v.x); pk.h[1] = f2bf(v.y); pk.h[2] = f2bf(v.z); pk.h[3] = f2bf(v.w);
  *reinterpret_cast<uint2*>(out + i) = pk.u;
}

// three equal-size fp32 matrices -> one contiguous bf16 buffer
__global__ __launch_bounds__(256) void cvt3_kernel(const float* __restrict__ a,
                                                   const float* __restrict__ b,
                                                   const float* __restrict__ c,
                                                   __hip_bfloat16* __restrict__ out, int n) {
  int i = (blockIdx.x * 256 + threadIdx.x) * 4;
  if (i >= 3 * n) return;
  const float* src = (i < n) ? (a + i) : (i < 2 * n) ? (b + i - n) : (c + i - 2 * n);
  float4 v = *reinterpret_cast<const float4*>(src);
  union { __hip_bfloat16 h[4]; uint2 u; } pk;
  pk.h[0] = f2bf(v.x); pk.h[1] = f2bf(v.y); pk.h[2] = f2bf(v.z); pk.h[3] = f2bf(v.w);
  *reinterpret_cast<uint2*>(out + i) = pk.u;
}

// w1,w3 -> interleaved bf16 buffer: B row br = 32g + j; j<16 -> w1[g*16+j], else w3[g*16+j-16].
__global__ __launch_bounds__(256) void cvt_swiglu(const float* __restrict__ w1,
                                                  const float* __restrict__ w3,
                                                  __hip_bfloat16* __restrict__ out) {
  const size_t i = ((size_t)blockIdx.x * 256 + threadIdx.x) * 4;  // < 11264*2048
  const int br = (int)(i >> 11);
  const int k  = (int)(i & 2047);
  const int g  = br >> 5, j = br & 31;
  const int srow = g * 16 + (j & 15);
  union { __hip_bfloat16 h[4]; uint2 u; } pk;
  if (srow < DFF) {
    const float* src = (j < 16 ? w1 : w3) + (size_t)srow * DM + k;
    float4 v = *reinterpret_cast<const float4*>(src);
    pk.h[0] = f2bf(v.x); pk.h[1] = f2bf(v.y); pk.h[2] = f2bf(v.z); pk.h[3] = f2bf(v.w);
  } else {
    pk.u.x = 0u; pk.u.y = 0u;
  }
  *reinterpret_cast<uint2*>(out + i) = pk.u;
}

// ---------------- RMSNorm: fp32 in -> bf16 out ----------------
__global__ __launch_bounds__(256) void rmsnorm_kernel(const float* __restrict__ x,
                                                      const float* __restrict__ g,
                                                      __hip_bfloat16* __restrict__ out) {
  const int row = blockIdx.x, tid = threadIdx.x;
  const float4* xr = reinterpret_cast<const float4*>(x + (size_t)row * DM);
  float4 a = xr[tid], b = xr[tid + 256];
  float ss = a.x*a.x + a.y*a.y + a.z*a.z + a.w*a.w
           + b.x*b.x + b.y*b.y + b.z*b.z + b.w*b.w;
#pragma unroll
  for (int off = 1; off < 64; off <<= 1) ss += __shfl_xor(ss, off);
  __shared__ float red[4];
  if ((tid & 63) == 0) red[tid >> 6] = ss;
  __syncthreads();
  const float inv = rsqrtf((red[0] + red[1] + red[2] + red[3]) * (1.0f / DM) + 1e-5f);
  const float4* gr = reinterpret_cast<const float4*>(g);
  float4 ga = gr[tid], gb = gr[tid + 256];
  union { __hip_bfloat16 h[4]; uint2 u; } pa, pb;
  pa.h[0] = f2bf(a.x * inv * ga.x); pa.h[1] = f2bf(a.y * inv * ga.y);
  pa.h[2] = f2bf(a.z * inv * ga.z); pa.h[3] = f2bf(a.w * inv * ga.w);
  pb.h[0] = f2bf(b.x * inv * gb.x); pb.h[1] = f2bf(b.y * inv * gb.y);
  pb.h[2] = f2bf(b.z * inv * gb.z); pb.h[3] = f2bf(b.w * inv * gb.w);
  uint2* o = reinterpret_cast<uint2*>(out + (size_t)row * DM);
  o[tid] = pa.u; o[tid + 256] = pb.u;
}

// ---------------- RoPE in-place on qkv: Q and K in one pass; Q scaled by log2e/sqrt(dk) ----
__global__ __launch_bounds__(256) void rope_kernel(__hip_bfloat16* __restrict__ t,
                                                   const int* __restrict__ pos) {
  const size_t idx = (size_t)blockIdx.x * 256 + threadIdx.x; // S*NH*64
  const int j = (int)(idx & 63);
  const int h = (int)((idx >> 6) & 15);
  const int s = (int)(idx >> 10);
  const float p = (float)pos[s];
  const float freq = exp2f((float)j * (-13.287712379549449f / 64.0f));
  float sn, cs;
  sincosf(p * freq, &sn, &cs);
  const float cl2 = 1.4426950408889634f * 0.08838834764831845f; // log2e / sqrt(128)
  __hip_bfloat16* ptrQ = t + (size_t)s * QLD + h * DK + 2 * j;
  __hip_bfloat16* ptrK = ptrQ + DM;
  {
    const float e = bf2f(ptrQ[0]), o = bf2f(ptrQ[1]);
    ptrQ[0] = f2bf((e * cs - o * sn) * cl2);
    ptrQ[1] = f2bf((e * sn + o * cs) * cl2);
  }
  {
    const float e = bf2f(ptrK[0]), o = bf2f(ptrK[1]);
    ptrK[0] = f2bf(e * cs - o * sn);
    ptrK[1] = f2bf(e * sn + o * cs);
  }
}

// ---------------- V transpose: qkv[:, 2*DM + h*DK + d] -> vt[h][d][s] ----------------
__global__ __launch_bounds__(256) void transpose_v(const __hip_bfloat16* __restrict__ qkv,
                                                   __hip_bfloat16* __restrict__ vt) {
  __shared__ __hip_bfloat16 tile[64][65];
  const int h = blockIdx.z;
  const int s0 = blockIdx.x * 64, d0 = blockIdx.y * 64;
  const int lane = threadIdx.x & 63, w = threadIdx.x >> 6;
#pragma unroll
  for (int i = 0; i < 16; i++) {
    const int r = w * 16 + i;
    tile[r][lane] = qkv[(size_t)(s0 + r) * QLD + 2 * DM + h * DK + d0 + lane];
  }
  __syncthreads();
#pragma unroll
  for (int i = 0; i < 16; i++) {
    const int r = w * 16 + i;
    vt[(size_t)(h * DK + d0 + r) * S_ + s0 + lane] = tile[lane][r];
  }
}

enum { EP_BF16 = 0, EP_SILU = 1, EP_MUL = 2, EP_ADDF32 = 3, EP_SWIGLU = 4 };

// ================= gemm2 (proven r4/r7 core, 1 barrier/K-tile): BM=128,BN=256,BK=32 ====
template <int EP>
__global__ __launch_bounds__(512, 2) void gemm2(const __hip_bfloat16* __restrict__ A,
                                                const __hip_bfloat16* __restrict__ B,
                                                int N, int K, int lda, int ldb,
                                                void* outp, const void* extra) {
  __shared__ char lds[3][24576];
  const int tid = threadIdx.x;
  const int wave = tid >> 6, lane = tid & 63;
  const int l15 = lane & 15, l4 = lane >> 4;
  const int wm = wave >> 2, wn = wave & 3;

  const int nbn = gridDim.x;
  const int nwg = gridDim.x * gridDim.y;
  int lin = blockIdx.y * gridDim.x + blockIdx.x;
  if ((nwg & 7) == 0) lin = (lin & 7) * (nwg >> 3) + (lin >> 3);
  const int bm = (lin / nbn) * 128;
  const int bn = (lin % nbn) * 256;

  const int NT = K >> 5;

  const int srcCh = ((tid & 3) ^ ((tid >> 3) & 3)) * 16;
  const char* Asrc  = (const char*)A + (size_t)(bm + (tid >> 2)) * lda * 2 + srcCh;
  const char* Bsrc0 = (const char*)B + (size_t)(bn + (tid >> 2)) * ldb * 2 + srcCh;
  const char* Bsrc1 = (const char*)B + (size_t)(bn + 128 + (tid >> 2)) * ldb * 2 + srcCh;
  char* const ldsA  = &lds[0][0] + wave * 1024;
  char* const ldsB0 = &lds[0][0] + 8192 + wave * 1024;
  char* const ldsB1 = &lds[0][0] + 16384 + wave * 1024;

  auto stage_a  = [&](int t, int s) { async_ld16(ldsA  + s * 24576, Asrc  + (size_t)t * 64); };
  auto stage_b0 = [&](int t, int s) { async_ld16(ldsB0 + s * 24576, Bsrc0 + (size_t)t * 64); };
  auto stage_b1 = [&](int t, int s) { async_ld16(ldsB1 + s * 24576, Bsrc1 + (size_t)t * 64); };

  const int rdch = (l4 ^ ((l15 >> 1) & 3)) * 16;
  auto rd_a = [&](int s, int mq, int f) -> s16x8 {
    return *(const s16x8*)(&lds[s][0] + (wm * 64 + mq * 32 + f * 16 + l15) * 64 + rdch);
  };
  auto rd_b = [&](int s, int nf) -> s16x8 {
    return *(const s16x8*)(&lds[s][8192] + (wn * 64 + nf * 16 + l15) * 64 + rdch);
  };

  f32x4 acc[4][4] = {};

  stage_a(0, 0); stage_b0(0, 0); stage_b1(0, 0);
  stage_a(1, 1); stage_b0(1, 1); stage_b1(1, 1);

  for (int t = 0; t < NT; t++) {
    const int s = t % 3;
    if (t + 1 < NT) { asm volatile("s_waitcnt vmcnt(3)" ::: "memory"); }
    else            { asm volatile("s_waitcnt vmcnt(0)" ::: "memory"); }
    __builtin_amdgcn_s_barrier();
    asm volatile("" ::: "memory");
    s16x8 b0 = rd_b(s, 0), b1 = rd_b(s, 1), b2 = rd_b(s, 2), b3 = rd_b(s, 3);
    s16x8 a0 = rd_a(s, 0, 0), a1 = rd_a(s, 0, 1);
    if (t + 2 < NT) { const int s2 = (t + 2) % 3; stage_a(t + 2, s2); stage_b0(t + 2, s2); }
    __builtin_amdgcn_s_setprio(1);
    acc[0][0] = MFMA_BF16(a0, b0, acc[0][0]);
    acc[0][1] = MFMA_BF16(a0, b1, acc[0][1]);
    acc[0][2] = MFMA_BF16(a0, b2, acc[0][2]);
    acc[0][3] = MFMA_BF16(a0, b3, acc[0][3]);
    acc[1][0] = MFMA_BF16(a1, b0, acc[1][0]);
    acc[1][1] = MFMA_BF16(a1, b1, acc[1][1]);
    acc[1][2] = MFMA_BF16(a1, b2, acc[1][2]);
    acc[1][3] = MFMA_BF16(a1, b3, acc[1][3]);
    __builtin_amdgcn_s_setprio(0);
    s16x8 a2 = rd_a(s, 1, 0), a3 = rd_a(s, 1, 1);
    if (t + 2 < NT) stage_b1(t + 2, (t + 2) % 3);
    __builtin_amdgcn_s_setprio(1);
    acc[2][0] = MFMA_BF16(a2, b0, acc[2][0]);
    acc[2][1] = MFMA_BF16(a2, b1, acc[2][1]);
    acc[2][2] = MFMA_BF16(a2, b2, acc[2][2]);
    acc[2][3] = MFMA_BF16(a2, b3, acc[2][3]);
    acc[3][0] = MFMA_BF16(a3, b0, acc[3][0]);
    acc[3][1] = MFMA_BF16(a3, b1, acc[3][1]);
    acc[3][2] = MFMA_BF16(a3, b2, acc[3][2]);
    acc[3][3] = MFMA_BF16(a3, b3, acc[3][3]);
    __builtin_amdgcn_s_setprio(0);
  }

#pragma unroll
  for (int mf = 0; mf < 4; mf++)
#pragma unroll
    for (int nf = 0; nf < 4; nf++)
#pragma unroll
      for (int r = 0; r < 4; r++) {
        const int row = bm + wm * 64 + mf * 16 + l4 * 4 + r;
        const int col = bn + wn * 64 + nf * 16 + l15;
        const size_t idx = (size_t)row * N + col;
        const float v = acc[mf][nf][r];
        if constexpr (EP == EP_BF16) {
          ((__hip_bfloat16*)outp)[idx] = f2bf(v);
        } else if constexpr (EP == EP_SILU) {
          ((__hip_bfloat16*)outp)[idx] = f2bf(v / (1.0f + __expf(-v)));
        } else if constexpr (EP == EP_MUL) {
          const float o = bf2f(((const __hip_bfloat16*)extra)[idx]);
          ((__hip_bfloat16*)outp)[idx] = f2bf(v * o);
        } else { // EP_ADDF32
          ((float*)outp)[idx] = v + ((const float*)extra)[idx];
        }
      }
}

// ================= gemm4 (r10 proven form): BM=BN=256, BK=32, 4-slot, depth-3 ============
template <int EP>
__global__ __launch_bounds__(512, 1) void gemm4(const __hip_bfloat16* __restrict__ A,
                                                const __hip_bfloat16* __restrict__ B,
                                                int N, int K, int lda, int ldb,
                                                void* outp, const void* extra) {
  __shared__ char lds[4][32768];   // slot: A[256][64B] @0, B[256][64B] @16384
  const int tid = threadIdx.x;
  const int wave = tid >> 6, lane = tid & 63;
  const int l15 = lane & 15, l4 = lane >> 4;
  const int wm = wave >> 2, wn = wave & 3;   // wm 0..1, wn 0..3

  const int nbn = gridDim.x;
  const int nwg = gridDim.x * gridDim.y;
  int lin = blockIdx.y * gridDim.x + blockIdx.x;
  if ((nwg & 7) == 0) lin = (lin & 7) * (nwg >> 3) + (lin >> 3);
  const int bm = (lin / nbn) * 256;
  const int bn = (lin % nbn) * 256;

  const int NT = K >> 5;

  const int srcCh = ((tid & 3) ^ ((tid >> 3) & 3)) * 16;
  const char* Asrc0 = (const char*)A + (size_t)(bm + (tid >> 2)) * lda * 2 + srcCh;
  const char* Asrc1 = (const char*)A + (size_t)(bm + 128 + (tid >> 2)) * lda * 2 + srcCh;
  const char* Bsrc0 = (const char*)B + (size_t)(bn + (tid >> 2)) * ldb * 2 + srcCh;
  const char* Bsrc1 = (const char*)B + (size_t)(bn + 128 + (tid >> 2)) * ldb * 2 + srcCh;
  char* const ldsA0 = &lds[0][0] + wave * 1024;
  char* const ldsA1 = &lds[0][0] + 8192 + wave * 1024;
  char* const ldsB0 = &lds[0][0] + 16384 + wave * 1024;
  char* const ldsB1 = &lds[0][0] + 24576 + wave * 1024;

  auto stage_a0 = [&](int t, int s) { async_ld16(ldsA0 + s * 32768, Asrc0 + (size_t)t * 64); };
  auto stage_a1 = [&](int t, int s) { async_ld16(ldsA1 + s * 32768, Asrc1 + (size_t)t * 64); };
  auto stage_b0 = [&](int t, int s) { async_ld16(ldsB0 + s * 32768, Bsrc0 + (size_t)t * 64); };
  auto stage_b1 = [&](int t, int s) { async_ld16(ldsB1 + s * 32768, Bsrc1 + (size_t)t * 64); };

  const int rdch = (l4 ^ ((l15 >> 1) & 3)) * 16;
  auto rd_a = [&](int s, int mf) -> s16x8 {
    return *(const s16x8*)(&lds[s][0] + (wm * 128 + mf * 16 + l15) * 64 + rdch);
  };
  auto rd_b = [&](int s, int nf) -> s16x8 {
    return *(const s16x8*)(&lds[s][16384] + (wn * 64 + nf * 16 + l15) * 64 + rdch);
  };

  f32x4 acc[8][4] = {};

#pragma unroll
  for (int t = 0; t < 3; t++) {
    stage_a0(t, t); stage_a1(t, t); stage_b0(t, t); stage_b1(t, t);
  }

  for (int t = 0; t < NT; t++) {
    const int s = t & 3;
    if (t + 1 < NT) { asm volatile("s_waitcnt vmcnt(8)" ::: "memory"); }
    else            { asm volatile("s_waitcnt vmcnt(0)" ::: "memory"); }
    __builtin_amdgcn_s_barrier();
    asm volatile("" ::: "memory");
    const int s3 = (t + 3) & 3;
    const bool pf = (t + 3 < NT);
    s16x8 b0 = rd_b(s, 0), b1 = rd_b(s, 1), b2 = rd_b(s, 2), b3 = rd_b(s, 3);
    // phase 0
    s16x8 a0 = rd_a(s, 0), a1 = rd_a(s, 1);
    if (pf) stage_a0(t + 3, s3);
    __builtin_amdgcn_s_setprio(1);
    acc[0][0] = MFMA_BF16(a0, b0, acc[0][0]);
    acc[0][1] = MFMA_BF16(a0, b1, acc[0][1]);
    acc[0][2] = MFMA_BF16(a0, b2, acc[0][2]);
    acc[0][3] = MFMA_BF16(a0, b3, acc[0][3]);
    acc[1][0] = MFMA_BF16(a1, b0, acc[1][0]);
    acc[1][1] = MFMA_BF16(a1, b1, acc[1][1]);
    acc[1][2] = MFMA_BF16(a1, b2, acc[1][2]);
    acc[1][3] = MFMA_BF16(a1, b3, acc[1][3]);
    __builtin_amdgcn_s_setprio(0);
    // phase 1
    s16x8 a2 = rd_a(s, 2), a3 = rd_a(s, 3);
    if (pf) stage_a1(t + 3, s3);
    __builtin_amdgcn_s_setprio(1);
    acc[2][0] = MFMA_BF16(a2, b0, acc[2][0]);
    acc[2][1] = MFMA_BF16(a2, b1, acc[2][1]);
    acc[2][2] = MFMA_BF16(a2, b2, acc[2][2]);
    acc[2][3] = MFMA_BF16(a2, b3, acc[2][3]);
    acc[3][0] = MFMA_BF16(a3, b0, acc[3][0]);
    acc[3][1] = MFMA_BF16(a3, b1, acc[3][1]);
    acc[3][2] = MFMA_BF16(a3, b2, acc[3][2]);
    acc[3][3] = MFMA_BF16(a3, b3, acc[3][3]);
    __builtin_amdgcn_s_setprio(0);
    // phase 2
    s16x8 a4 = rd_a(s, 4), a5 = rd_a(s, 5);
    if (pf) stage_b0(t + 3, s3);
    __builtin_amdgcn_s_setprio(1);
    acc[4][0] = MFMA_BF16(a4, b0, acc[4][0]);
    acc[4][1] = MFMA_BF16(a4, b1, acc[4][1]);
    acc[4][2] = MFMA_BF16(a4, b2, acc[4][2]);
    acc[4][3] = MFMA_BF16(a4, b3, acc[4][3]);
    acc[5][0] = MFMA_BF16(a5, b0, acc[5][0]);
    acc[5][1] = MFMA_BF16(a5, b1, acc[5][1]);
    acc[5][2] = MFMA_BF16(a5, b2, acc[5][2]);
    acc[5][3] = MFMA_BF16(a5, b3, acc[5][3]);
    __builtin_amdgcn_s_setprio(0);
    // phase 3
    s16x8 a6 = rd_a(s, 6), a7 = rd_a(s, 7);
    if (pf) stage_b1(t + 3, s3);
    __builtin_amdgcn_s_setprio(1);
    acc[6][0] = MFMA_BF16(a6, b0, acc[6][0]);
    acc[6][1] = MFMA_BF16(a6, b1, acc[6][1]);
    acc[6][2] = MFMA_BF16(a6, b2, acc[6][2]);
    acc[6][3] = MFMA_BF16(a6, b3, acc[6][3]);
    acc[7][0] = MFMA_BF16(a7, b0, acc[7][0]);
    acc[7][1] = MFMA_BF16(a7, b1, acc[7][1]);
    acc[7][2] = MFMA_BF16(a7, b2, acc[7][2]);
    acc[7][3] = MFMA_BF16(a7, b3, acc[7][3]);
    __builtin_amdgcn_s_setprio(0);
  }

  if constexpr (EP == EP_SWIGLU) {
#pragma unroll
    for (int mf = 0; mf < 8; mf++)
#pragma unroll
      for (int pp = 0; pp < 2; pp++)
#pragma unroll
        for (int r = 0; r < 4; r++) {
          const int row = bm + wm * 128 + mf * 16 + l4 * 4 + r;
          const int col = (bn >> 1) + wn * 32 + pp * 16 + l15;
          const float gt = acc[mf][pp * 2][r];
          const float up = acc[mf][pp * 2 + 1][r];
          ((__hip_bfloat16*)outp)[(size_t)row * N + col] =
              f2bf(gt / (1.0f + __expf(-gt)) * up);
        }
    return;
  }

#pragma unroll
  for (int mf = 0; mf < 8; mf++)
#pragma unroll
    for (int nf = 0; nf < 4; nf++)
#pragma unroll
      for (int r = 0; r < 4; r++) {
        const int row = bm + wm * 128 + mf * 16 + l4 * 4 + r;
        const int col = bn + wn * 64 + nf * 16 + l15;
        const size_t idx = (size_t)row * N + col;
        const float v = acc[mf][nf][r];
        if constexpr (EP == EP_ADDF32) {
          ((float*)outp)[idx] = v + ((const float*)extra)[idx];
        } else {
          ((__hip_bfloat16*)outp)[idx] = f2bf(v);
        }
      }
}

// ---------------- causal flash attention (r9 v4, best measured: pairing + K/V dbuf) -----
__global__ __launch_bounds__(256, 2) void attn_kernel(const __hip_bfloat16* __restrict__ qkv,
                                                      const __hip_bfloat16* __restrict__ vt,
                                                      __hip_bfloat16* __restrict__ out) {
  __shared__ char sK[2][64 * 256];  // [kv][d] 2x16KB
  __shared__ char sV[2][128 * 128]; // [d][kv] 2x16KB

  const int h = blockIdx.y;
  int qt = (blockIdx.x + 2 * (h & 7)) & 31;
  if (h >= 8) qt = 31 - qt;
  const int qtile = qt;
  const int q0 = qtile * 128;
  const int tid = threadIdx.x, wave = tid >> 6, lane = tid & 63;
  const int l31 = lane & 31, hi = lane >> 5;
  const int qr = q0 + wave * 32 + l31;           // this lane's q row
  const int ntiles = qtile * 2 + 2;

  s16x8 qf[8];
  {
    const char* qsrc = (const char*)qkv + (size_t)qr * (QLD * 2) + h * DK * 2 + hi * 16;
#pragma unroll
    for (int s = 0; s < 8; s++) qf[s] = *(const s16x8*)(qsrc + s * 32);
  }

  const char* qkvK = (const char*)qkv + ((size_t)DM + h * DK) * 2;
  const char* vtH  = (const char*)vt + (size_t)h * DK * S_ * 2;

  auto stage_K = [&](int t, int buf) {
    const int kv0 = t * 64;
#pragma unroll
    for (int a = 0; a < 4; a++) {
      const int rl = wave * 16 + a * 4 + (lane >> 4);
      const int ck = (lane & 15) ^ (rl & 7);
      async_ld16(sK[buf] + (wave * 16 + a * 4) * 256,
                 qkvK + (size_t)(kv0 + rl) * (QLD * 2) + ck * 16);
    }
  };
  auto stage_V = [&](int t, int buf) {
    const int kv0 = t * 64;
#pragma unroll
    for (int a = 0; a < 4; a++) {
      const int rl = wave * 32 + a * 8 + (lane >> 3);
      const int cv = (lane & 7) ^ (rl & 7);
      async_ld16(sV[buf] + (wave * 32 + a * 8) * 128,
                 vtH + ((size_t)rl * S_ + kv0) * 2 + cv * 16);
    }
  };

  f32x16 acc[4] = {};
  float m_ = -__builtin_inff(), l_ = 0.f;

  stage_K(0, 0);
  stage_V(0, 0);

  int buf = 0;
  for (int t = 0; t < ntiles; t++) {
    if (t + 1 < ntiles) {
      stage_K(t + 1, buf ^ 1);
      stage_V(t + 1, buf ^ 1);
      asm volatile("s_waitcnt vmcnt(8)" ::: "memory");
    } else {
      asm volatile("s_waitcnt vmcnt(0)" ::: "memory");
    }
    __builtin_amdgcn_s_barrier();

    const char* Kt = sK[buf];
    const char* Vt = sV[buf];

    f32x16 st0 = {}, st1 = {};
    __builtin_amdgcn_s_setprio(1);
#pragma unroll
    for (int s = 0; s < 8; s++) {
      const int cc = s * 2 + hi;
      const int cs = (cc & 8) | ((cc ^ l31) & 7);
      s16x8 k0 = *(const s16x8*)(Kt + l31 * 256 + cs * 16);
      s16x8 k1 = *(const s16x8*)(Kt + (32 + l31) * 256 + cs * 16);
      st0 = MFMA32(k0, qf[s], st0);
      st1 = MFMA32(k1, qf[s], st1);
    }
    __builtin_amdgcn_s_setprio(0);

    const int kvb = t * 64;
    float p[32];
    float mx = -__builtin_inff();
    if (kvb + 63 <= q0 + wave * 32) {
#pragma unroll
      for (int r = 0; r < 16; r++) {
        p[r]      = st0[r];
        p[16 + r] = st1[r];
        mx = fmaxf(mx, fmaxf(p[r], p[16 + r]));
      }
    } else {
#pragma unroll
      for (int r = 0; r < 16; r++) {
        const int kv = kvb + (r & 3) + 8 * (r >> 2) + 4 * hi;
        p[r]      = (kv <= qr)      ? st0[r] : -__builtin_inff();
        p[16 + r] = (kv + 32 <= qr) ? st1[r] : -__builtin_inff();
        mx = fmaxf(mx, fmaxf(p[r], p[16 + r]));
      }
    }
    mx = fmaxf(mx, __shfl_xor(mx, 32));
    const bool skip = __all(mx - m_ <= 8.0f);
    float alpha = 1.0f;
    if (!skip) {
      const float nm = fmaxf(m_, mx);
      alpha = exp2f(m_ - nm);
      m_ = nm;
#pragma unroll
      for (int dt = 0; dt < 4; dt++)
#pragma unroll
        for (int r = 0; r < 16; r++) acc[dt][r] *= alpha;
    }
    float psum = 0.f;
#pragma unroll
    for (int i = 0; i < 32; i++) {
      p[i] = exp2f(p[i] - m_);
      psum += p[i];
    }
    psum += __shfl_xor(psum, 32);
    l_ = l_ * alpha + psum;

    unsigned ps[16];
#pragma unroll
    for (int h2 = 0; h2 < 2; h2++)
#pragma unroll
      for (int t2 = 0; t2 < 4; t2++)
#pragma unroll
        for (int rp = 0; rp < 2; rp++) {
          union { __hip_bfloat16 hh[2]; unsigned u; } pk;
          pk.hh[0] = f2bf(p[h2 * 16 + t2 * 4 + rp * 2]);
          pk.hh[1] = f2bf(p[h2 * 16 + t2 * 4 + rp * 2 + 1]);
          ps[h2 * 8 + t2 * 2 + rp] = pk.u;
        }

#pragma unroll
    for (int s = 0; s < 4; s++) {
      const int h2 = s >> 1;
      const int iA = h2 * 8 + (2 * (s & 1)) * 2;
      const int iB = h2 * 8 + (2 * (s & 1) + 1) * 2;
      const unsigned keep0 = hi ? ps[iB]     : ps[iA];
      const unsigned keep1 = hi ? ps[iB + 1] : ps[iA + 1];
      const unsigned send0 = hi ? ps[iA]     : ps[iB];
      const unsigned send1 = hi ? ps[iA + 1] : ps[iB + 1];
      const unsigned recv0 = __shfl_xor(send0, 32);
      const unsigned recv1 = __shfl_xor(send1, 32);
      union { unsigned u[4]; s16x8 v; } fr;
      fr.u[0] = hi ? recv0 : keep0;
      fr.u[1] = hi ? recv1 : keep1;
      fr.u[2] = hi ? keep0 : recv0;
      fr.u[3] = hi ? keep1 : recv1;
      const s16x8 pa = fr.v;
      __builtin_amdgcn_s_setprio(1);
#pragma unroll
      for (int dt = 0; dt < 4; dt++) {
        s16x8 vf = *(const s16x8*)(Vt + (dt * 32 + l31) * 128 +
                                   (((s * 2 + hi) ^ (l31 & 7)) & 7) * 16);
        acc[dt] = MFMA32(vf, pa, acc[dt]);
      }
      __builtin_amdgcn_s_setprio(0);
    }

    if (t + 2 < ntiles) __builtin_amdgcn_s_barrier();
    buf ^= 1;
  }

  const float rl = 1.0f / l_;
  __hip_bfloat16* orow = out + (size_t)qr * DM + h * DK;
#pragma unroll
  for (int dt = 0; dt < 4; dt++)
#pragma unroll
    for (int rq = 0; rq < 4; rq++) {
      union { __hip_bfloat16 hh[4]; uint2 u; } pk;
#pragma unroll
      for (int e = 0; e < 4; e++) pk.hh[e] = f2bf(acc[dt][rq * 4 + e] * rl);
      *reinterpret_cast<uint2*>(orow + dt * 32 + 8 * rq + 4 * hi) = pk.u;
    }
}

// ---------------- host launcher ----------------
// Workspace (109,051,904 B), phase-overlaid:
//  attn phase: wqkv@0 (25.2M) [attnb@8.4M after], xn@25.2M (16.8M), qkv@42M (50.3M), vt@92.3M (16.8M)
//  WO:         wo@0 (8.4M), attnb@8.4M, x1 -> d_out
//  FFN phase:  xn2@0 (16.8M), wfused@16.8M (46.1M), ff1@62.9M (46.1M); then w2@0 (22.5M)
extern "C" void kernel_launch(void* const* d_in, const int* in_sizes, int n_in,
                              void* d_out, int out_size, void* d_ws, size_t ws_size,
                              hipStream_t stream) {
  const float* x   = (const float*)d_in[0];
  const float* w_q = (const float*)d_in[1];
  const float* w_k = (const float*)d_in[2];
  const float* w_v = (const float*)d_in[3];
  const float* w_o = (const float*)d_in[4];
  const float* w1  = (const float*)d_in[5];
  const float* w2  = (const float*)d_in[6];
  const float* w3  = (const float*)d_in[7];
  const float* g1  = (const float*)d_in[8];
  const float* g2  = (const float*)d_in[9];
  const int*   tp  = (const int*)d_in[10];
  float* outf = (float*)d_out;

  constexpr size_t SZ_WQKV  = (size_t)3 * DM * DM * 2;
  constexpr size_t OFF_ATTN = (size_t)DM * DM * 2;
  constexpr size_t OFF_XN   = SZ_WQKV;
  constexpr size_t OFF_A2   = OFF_XN + (size_t)S_ * DM * 2;
  constexpr size_t OFF_VT   = OFF_A2 + (size_t)S_ * QLD * 2;
  constexpr size_t WS_NEED  = OFF_VT + (size_t)NH * DK * S_ * 2;
  constexpr size_t OFF_WF   = (size_t)S_ * DM * 2;
  constexpr size_t OFF_FF1  = OFF_WF + (size_t)2 * DFFP * DM * 2;
  static_assert(OFF_FF1 + (size_t)S_ * DFFP * 2 == WS_NEED, "ws layout");
  if (ws_size < WS_NEED) return;

  char* base = (char*)d_ws;
  __hip_bfloat16* warena = (__hip_bfloat16*)base;
  __hip_bfloat16* attnb  = (__hip_bfloat16*)(base + OFF_ATTN);
  __hip_bfloat16* xn     = (__hip_bfloat16*)(base + OFF_XN);
  __hip_bfloat16* qkv    = (__hip_bfloat16*)(base + OFF_A2);
  __hip_bfloat16* vt     = (__hip_bfloat16*)(base + OFF_VT);
  __hip_bfloat16* xn2    = (__hip_bfloat16*)base;
  __hip_bfloat16* wfused = (__hip_bfloat16*)(base + OFF_WF);
  __hip_bfloat16* ff1    = (__hip_bfloat16*)(base + OFF_FF1);

  const int nwq = DM * DM;

  // --- attention phase ---
  cvt3_kernel<<<(3 * nwq) / 1024, 256, 0, stream>>>(w_q, w_k, w_v, warena, nwq);
  rmsnorm_kernel<<<S_, 256, 0, stream>>>(x, g1, xn);
  // qkv = xn @ Wqkv^T : gemm2, grid 24x32=768 (%8==0, 2 blocks/CU)
  gemm2<EP_BF16><<<dim3(QLD / 256, S_ / 128), 512, 0, stream>>>(xn, warena, QLD, DM, DM, DM, qkv, nullptr);
  rope_kernel<<<(S_ * NH * 64) / 256, 256, 0, stream>>>(qkv, tp);
  transpose_v<<<dim3(S_ / 64, DK / 64, NH), 256, 0, stream>>>(qkv, vt);
  // attn v4: grid 32x16=512 blocks, 4 waves, 2 blocks/CU, complementary pairing
  attn_kernel<<<dim3(S_ / 128, NH), 256, 0, stream>>>(qkv, vt, attnb);
  // x1 = x + attn @ Wo^T : gemm2, grid 8x32=256
  cvt_kernel<<<nwq / 1024, 256, 0, stream>>>(w_o, warena, nwq);
  gemm2<EP_ADDF32><<<dim3(DM / 256, S_ / 128), 512, 0, stream>>>(attnb, warena, DM, DM, DM, DM, outf, x);

  // --- FFN phase ---
  rmsnorm_kernel<<<S_, 256, 0, stream>>>(outf, g2, xn2);
  cvt_swiglu<<<(2 * DFFP * DM) / 1024, 256, 0, stream>>>(w1, w3, wfused);
  // ff1 = silu(xn2 @ W1^T) * (xn2 @ W3^T) : gemm4 (r10 form), grid 44x16=704, out stride DFFP
  gemm4<EP_SWIGLU><<<dim3((2 * DFFP) / 256, S_ / 256), 512, 0, stream>>>(xn2, wfused, DFFP, DM, DM, DM, ff1, nullptr);
  // out = x1 + ff1 @ W2^T : gemm2, K=5504, lda=5632 (pad stride), grid 8x32=256
  cvt_kernel<<<(DM * DFF) / 1024, 256, 0, stream>>>(w2, warena, DM * DFF);
  gemm2<EP_ADDF32><<<dim3(DM / 256, S_ / 128), 512, 0, stream>>>(ff1, warena, DM, DFF, DFFP, DFF, outf, outf);
}